// Round 9
// baseline (620.552 us; speedup 1.0000x reference)
//
#include <hip/hip_runtime.h>

#define NUM_USERS 100000
#define NUM_ITEMS 50000
#define NUM_EDGES 4000000
#define DIM 64

// Source-table slicing: 1<<14 = 16384 rows/slice = 2 MB bf16 per slice
// (phase-major gather holds one slice per direction in L2; 2+2 MB = L2).
#define SLICE_SHIFT 14
#define SLICES_U ((NUM_USERS + (1 << SLICE_SHIFT) - 1) >> SLICE_SHIFT)  // 7
#define SLICES_I ((NUM_ITEMS + (1 << SLICE_SHIFT) - 1) >> SLICE_SHIFT)  // 4

#define N_I (SLICES_U * NUM_ITEMS)   // 350000 item-direction bins
#define N_U (SLICES_I * NUM_USERS)   // 400000 user-direction bins
#define N_TOTAL (N_I + N_U)          // 750000

#define SCAN_NB 512
#define SCAN_THREADS 256

// ---- two-level bucket partition --------------------------------------------
#define PCHUNK 4096                    // edges per partition workgroup
#define PWG ((NUM_EDGES + PCHUNK - 1) / PCHUNK)   // 977
#define BUK_SHIFT 10                   // 1024 bins per bucket
#define BUK_BINS (1 << BUK_SHIFT)
#define NBUK_I ((N_I + BUK_BINS - 1) >> BUK_SHIFT)   // 342
#define NBUK_U ((N_U + BUK_BINS - 1) >> BUK_SHIFT)   // 391
#define NBUK (NBUK_I + NBUK_U)                       // 733

#define STAGE_CAP 15360
#define BF_THREADS 512

// Gather: each wave owns 8 contiguous rows; merged directions; paired records.
#define GW_ROWS 8

// Packed CSR record: (src_row << 15) | w_quant15 (err <= 1.5e-5 << bf16 noise).
#define W_SCALE 32767.0f
#define W_INV   (1.0f / 32767.0f)

// ---------------- fallback: scatter-atomic (round-1 kernel) ----------------
__global__ __launch_bounds__(256) void lightgcn_scatter(
    const float* __restrict__ user_emb,
    const float* __restrict__ item_emb,
    const float* __restrict__ edge_norm,
    const int* __restrict__ u_idx,
    const int* __restrict__ i_idx,
    float* __restrict__ agg_users,
    float* __restrict__ agg_items)
{
    long long gid = (long long)blockIdx.x * blockDim.x + threadIdx.x;
    int edge = (int)(gid >> 6);
    int lane = (int)(gid & 63);
    if (edge >= NUM_EDGES) return;
    int u = u_idx[edge];
    int i = i_idx[edge];
    float n = edge_norm[edge];
    float uval = user_emb[(size_t)u * DIM + lane];
    float ival = item_emb[(size_t)i * DIM + lane];
    atomicAdd(&agg_items[(size_t)i * DIM + lane], n * uval);
    atomicAdd(&agg_users[(size_t)u * DIM + lane], n * ival);
}

// ---------------- bf16 conversion of BOTH embedding tables -----------------
__global__ __launch_bounds__(256) void convert_both(
    const float4* __restrict__ usrc, const float4* __restrict__ isrc,
    ushort4* __restrict__ udst, ushort4* __restrict__ idst,
    int un4, int in4)
{
    int t = blockIdx.x * blockDim.x + threadIdx.x;
    const float4* s; ushort4* d; int idx;
    if (t < un4) { s = usrc; d = udst; idx = t; }
    else if (t < un4 + in4) { s = isrc; d = idst; idx = t - un4; }
    else return;
    float4 v = s[idx];
    ushort4 o;
    uint b;
    b = __float_as_uint(v.x); o.x = (ushort)((b + 0x7FFFu + ((b >> 16) & 1u)) >> 16);
    b = __float_as_uint(v.y); o.y = (ushort)((b + 0x7FFFu + ((b >> 16) & 1u)) >> 16);
    b = __float_as_uint(v.z); o.z = (ushort)((b + 0x7FFFu + ((b >> 16) & 1u)) >> 16);
    b = __float_as_uint(v.w); o.w = (ushort)((b + 0x7FFFu + ((b >> 16) & 1u)) >> 16);
    d[idx] = o;
}

// ---------------- phase A: per-WG bucket histograms (+ convert folded) ------
__global__ __launch_bounds__(256) void bucket_hist_conv(
    const int* __restrict__ u_idx, const int* __restrict__ i_idx,
    ushort* __restrict__ wgHist,
    const float4* __restrict__ usrc, const float4* __restrict__ isrc,
    ushort4* __restrict__ udst, ushort4* __restrict__ idst,
    int un4, int in4, int hist_blocks)
{
    __shared__ uint hist[NBUK];
    if ((int)blockIdx.x >= hist_blocks) {
        int ct = (blockIdx.x - hist_blocks) * blockDim.x + threadIdx.x;
        const float4* s; ushort4* d; int idx;
        if (ct < un4) { s = usrc; d = udst; idx = ct; }
        else if (ct < un4 + in4) { s = isrc; d = idst; idx = ct - un4; }
        else return;
        float4 v = s[idx];
        ushort4 o;
        uint b;
        b = __float_as_uint(v.x); o.x = (ushort)((b + 0x7FFFu + ((b >> 16) & 1u)) >> 16);
        b = __float_as_uint(v.y); o.y = (ushort)((b + 0x7FFFu + ((b >> 16) & 1u)) >> 16);
        b = __float_as_uint(v.z); o.z = (ushort)((b + 0x7FFFu + ((b >> 16) & 1u)) >> 16);
        b = __float_as_uint(v.w); o.w = (ushort)((b + 0x7FFFu + ((b >> 16) & 1u)) >> 16);
        d[idx] = o;
        return;
    }
    int t = threadIdx.x;
    for (int b = t; b < NBUK; b += 256) hist[b] = 0;
    __syncthreads();
    int e0 = blockIdx.x * PCHUNK;
    int ecnt = NUM_EDGES - e0; if (ecnt > PCHUNK) ecnt = PCHUNK;
    for (int k = t; k < ecnt; k += 256) {
        int u = u_idx[e0 + k];
        int i = i_idx[e0 + k];
        atomicAdd(&hist[((u >> SLICE_SHIFT) * NUM_ITEMS + i) >> BUK_SHIFT], 1u);
        atomicAdd(&hist[NBUK_I + (((i >> SLICE_SHIFT) * NUM_USERS + u) >> BUK_SHIFT)], 1u);
    }
    __syncthreads();
    ushort* row = wgHist + (size_t)blockIdx.x * NBUK;
    for (int b = t; b < NBUK; b += 256) row[b] = (ushort)hist[b];
}

// ---------------- phase B1: per-bucket scan over WGs (no atomics) -----------
__global__ __launch_bounds__(256) void mscan(
    const ushort* __restrict__ wgHist, uint* __restrict__ wgPrefixT,
    int* __restrict__ bukTot)
{
    __shared__ uint sm[256];
    int b = blockIdx.x, t = threadIdx.x;
    int i0 = t * 4;
    uint c0 = 0, c1 = 0, c2 = 0, c3 = 0;
    if (i0 + 0 < PWG) c0 = wgHist[(size_t)(i0 + 0) * NBUK + b];
    if (i0 + 1 < PWG) c1 = wgHist[(size_t)(i0 + 1) * NBUK + b];
    if (i0 + 2 < PWG) c2 = wgHist[(size_t)(i0 + 2) * NBUK + b];
    if (i0 + 3 < PWG) c3 = wgHist[(size_t)(i0 + 3) * NBUK + b];
    sm[t] = c0 + c1 + c2 + c3;
    __syncthreads();
    for (int o = 1; o < 256; o <<= 1) {
        uint x = (t >= o) ? sm[t - o] : 0;
        __syncthreads();
        sm[t] += x;
        __syncthreads();
    }
    uint excl = (t == 0) ? 0u : sm[t - 1];
    uint* orow = wgPrefixT + (size_t)b * PWG;
    if (i0 + 0 < PWG) orow[i0 + 0] = excl;
    if (i0 + 1 < PWG) orow[i0 + 1] = excl + c0;
    if (i0 + 2 < PWG) orow[i0 + 2] = excl + c0 + c1;
    if (i0 + 3 < PWG) orow[i0 + 3] = excl + c0 + c1 + c2;
    if (t == 255) bukTot[b] = (int)sm[255];
}

// ---------------- phase B2: scan 733 bucket totals (single WG) --------------
__global__ __launch_bounds__(256) void bucket_scan(
    const int* __restrict__ bukTot, int* __restrict__ bukOff,
    int* __restrict__ off_last)
{
    __shared__ int sm[256];
    int t = threadIdx.x;
    int b4 = t * 4;
    int v0 = 0, v1 = 0, v2 = 0, v3 = 0;
    if (b4 + 0 < NBUK) v0 = bukTot[b4 + 0];
    if (b4 + 1 < NBUK) v1 = bukTot[b4 + 1];
    if (b4 + 2 < NBUK) v2 = bukTot[b4 + 2];
    if (b4 + 3 < NBUK) v3 = bukTot[b4 + 3];
    sm[t] = v0 + v1 + v2 + v3;
    __syncthreads();
    for (int o = 1; o < 256; o <<= 1) {
        int x = (t >= o) ? sm[t - o] : 0;
        __syncthreads();
        sm[t] += x;
        __syncthreads();
    }
    int excl = (t == 0) ? 0 : sm[t - 1];
    if (b4 + 0 < NBUK) bukOff[b4 + 0] = excl;
    if (b4 + 1 < NBUK) bukOff[b4 + 1] = excl + v0;
    if (b4 + 2 < NBUK) bukOff[b4 + 2] = excl + v0 + v1;
    if (b4 + 3 < NBUK) bukOff[b4 + 3] = excl + v0 + v1 + v2;
    if (t == 255) bukOff[NBUK] = sm[255];
    if (t == 0) *off_last = 2 * NUM_EDGES;   // off[N_TOTAL]
}

// ---------------- phase C: per-WG LDS counting-sort into exact slabs --------
__global__ __launch_bounds__(256) void partition_pairs(
    const int* __restrict__ u_idx, const int* __restrict__ i_idx,
    const float* __restrict__ edge_norm,
    const ushort* __restrict__ wgHist, const uint* __restrict__ wgPrefixT,
    const int* __restrict__ bukOff,
    uint* __restrict__ pairRec, ushort* __restrict__ pairBin)
{
    __shared__ uint recS[2 * PCHUNK];   // 32 KB packed records, bucket-sorted
    __shared__ uint bbS[2 * PCHUNK];    // 32 KB (buk<<BUK_SHIFT)|lbin per slot
    __shared__ uint hist[NBUK];
    __shared__ uint cursor[NBUK];
    __shared__ uint gbase[NBUK];
    __shared__ uint scanTmp[256];

    int t  = threadIdx.x;
    int wg = blockIdx.x;
    int e0 = wg * PCHUNK;
    int ecnt = NUM_EDGES - e0; if (ecnt > PCHUNK) ecnt = PCHUNK;

    const ushort* hrow = wgHist + (size_t)wg * NBUK;
    for (int b = t; b < NBUK; b += 256) {
        hist[b]  = hrow[b];
        gbase[b] = (uint)bukOff[b] + wgPrefixT[(size_t)b * PWG + wg];
    }
    __syncthreads();

    // exclusive scan hist -> cursor
    int base4 = t * 4;
    uint v0 = 0, v1 = 0, v2 = 0, v3 = 0;
    if (base4 + 0 < NBUK) v0 = hist[base4 + 0];
    if (base4 + 1 < NBUK) v1 = hist[base4 + 1];
    if (base4 + 2 < NBUK) v2 = hist[base4 + 2];
    if (base4 + 3 < NBUK) v3 = hist[base4 + 3];
    scanTmp[t] = v0 + v1 + v2 + v3;
    __syncthreads();
    for (int o = 1; o < 256; o <<= 1) {
        uint x = (t >= o) ? scanTmp[t - o] : 0;
        __syncthreads();
        scanTmp[t] += x;
        __syncthreads();
    }
    uint excl = (t == 0) ? 0u : scanTmp[t - 1];
    if (base4 + 0 < NBUK) cursor[base4 + 0] = excl;
    if (base4 + 1 < NBUK) cursor[base4 + 1] = excl + v0;
    if (base4 + 2 < NBUK) cursor[base4 + 2] = excl + v0 + v1;
    if (base4 + 3 < NBUK) cursor[base4 + 3] = excl + v0 + v1 + v2;
    __syncthreads();

    // stage pairs into bucket-sorted LDS order
    for (int k = t; k < ecnt; k += 256) {
        int u = u_idx[e0 + k];
        int i = i_idx[e0 + k];
        float n = edge_norm[e0 + k];
        uint w = (uint)(n * W_SCALE + 0.5f); if (w > 32767u) w = 32767u;
        int binI = (u >> SLICE_SHIFT) * NUM_ITEMS + i;
        int binU = (i >> SLICE_SHIFT) * NUM_USERS + u;
        uint bI = (uint)(binI >> BUK_SHIFT);
        uint bU = (uint)(NBUK_I + (binU >> BUK_SHIFT));
        uint rI = atomicAdd(&cursor[bI], 1u);
        recS[rI] = ((uint)u << 15) | w;
        bbS[rI]  = (bI << BUK_SHIFT) | (uint)(binI & (BUK_BINS - 1));
        uint rU = atomicAdd(&cursor[bU], 1u);
        recS[rU] = ((uint)i << 15) | w;
        bbS[rU]  = (bU << BUK_SHIFT) | (uint)(binU & (BUK_BINS - 1));
    }
    __syncthreads();

    // write out sorted slots; consecutive slots -> consecutive global addrs
    int total = 2 * ecnt;
    for (int s = t; s < total; s += 256) {
        uint bb = bbS[s];
        uint b  = bb >> BUK_SHIFT;
        uint wb = cursor[b] - hist[b];           // bucket's local base in LDS
        uint lpos = gbase[b] + ((uint)s - wb);   // exact: always in range
        pairRec[lpos] = recS[s];
        pairBin[lpos] = (ushort)(bb & (BUK_BINS - 1));
    }
}

// ---------------- phase D: per-bucket CSR offsets + LDS-staged placement ----
__global__ __launch_bounds__(BF_THREADS) void bucket_fill(
    const int* __restrict__ bukOff,
    const uint* __restrict__ pairRec, const ushort* __restrict__ pairBin,
    int* __restrict__ off, uint* __restrict__ rec)
{
    __shared__ uint recS[STAGE_CAP];      // 60 KB
    __shared__ uint lcnt[BUK_BINS];       // 4 KB
    __shared__ uint cur[BUK_BINS];        // 4 KB
    __shared__ uint scanSm[BF_THREADS];   // 2 KB
    int b = blockIdx.x, t = threadIdx.x;
    lcnt[t] = 0; lcnt[t + BF_THREADS] = 0;
    __syncthreads();
    int s0 = bukOff[b], s1 = bukOff[b + 1];
    int n = s1 - s0;
    for (int k = t; k < n; k += BF_THREADS)
        atomicAdd(&lcnt[pairBin[s0 + k]], 1u);
    __syncthreads();
    // exclusive scan of 1024 counts, 2 per thread
    uint a0 = lcnt[2 * t], a1 = lcnt[2 * t + 1];
    scanSm[t] = a0 + a1;
    __syncthreads();
    for (int o = 1; o < BF_THREADS; o <<= 1) {
        uint x = (t >= o) ? scanSm[t - o] : 0;
        __syncthreads();
        scanSm[t] += x;
        __syncthreads();
    }
    uint excl = scanSm[t] - (a0 + a1);
    cur[2 * t]     = excl;
    cur[2 * t + 1] = excl + a0;
    // write CSR offsets for this bucket's real bins
    int gbin0, dirEnd;
    if (b < NBUK_I) { gbin0 = b << BUK_SHIFT; dirEnd = N_I; }
    else { gbin0 = N_I + ((b - NBUK_I) << BUK_SHIFT); dirEnd = N_TOTAL; }
    int lim = dirEnd - gbin0; if (lim > BUK_BINS) lim = BUK_BINS;
    if (2 * t     < lim) off[gbin0 + 2 * t]     = s0 + (int)excl;
    if (2 * t + 1 < lim) off[gbin0 + 2 * t + 1] = s0 + (int)(excl + a0);
    __syncthreads();   // cur[] visible before placement mutates it
    if (n <= STAGE_CAP) {
        for (int k = t; k < n; k += BF_THREADS) {
            uint lbin = pairBin[s0 + k];
            uint r = atomicAdd(&cur[lbin], 1u);
            recS[r] = pairRec[s0 + k];
        }
        __syncthreads();
        for (int k = t; k < n; k += BF_THREADS)   // linear, fully-coalesced
            rec[(size_t)s0 + k] = recS[k];
    } else {
        // exact fallback (never expected at this data scale)
        for (int k = t; k < n; k += BF_THREADS) {
            uint lbin = pairBin[s0 + k];
            uint r = atomicAdd(&cur[lbin], 1u);
            rec[(size_t)s0 + r] = pairRec[s0 + k];
        }
    }
}

// ---------------- phase E: merged phase-major gather, paired records --------
// Round-8. Round-7 proved phase-major slice sweeping gives near-perfect L2
// (FETCH 560->60 MB) but the per-direction launches were latency-bound
// (782 blocks = 31% occupancy, VALU 29%). Fixes:
//  (a) ONE launch for both directions: 18750 waves / 4688 blocks -> full occ.
//  (b) paired-record inner loop: lanes 0-31 process record A, lanes 32-63
//      record B; each lane loads ONE uint (2 bf16 dims) and keeps a float2
//      acc. Halves emb loads and cuts ~22 VALU instrs/record to ~7 (round-6
//      measured 69% VALU at 22/rec). One shfl_xor(32) at writeback merges
//      the half-wave partials; lanes 0-31 store float2 (256 B/row).
__global__ __launch_bounds__(256) void gather_pm(
    const int* __restrict__ off, const uint* __restrict__ rec,
    const uint* __restrict__ ue32, const uint* __restrict__ ie32,
    float* __restrict__ agg_users, float* __restrict__ agg_items)
{
    int wid  = (blockIdx.x * blockDim.x + threadIdx.x) >> 6;
    int lane = threadIdx.x & 63;
    const int IW = NUM_ITEMS / GW_ROWS;          // 6250 item-direction waves
    const uint* emb; float* outb; int r0, nspans, binBase, binStride;
    if (wid < IW) {
        r0 = wid * GW_ROWS;
        emb = ue32; outb = agg_items;
        nspans = SLICES_U; binBase = 0; binStride = NUM_ITEMS;
    } else {
        r0 = (wid - IW) * GW_ROWS;
        if (r0 >= NUM_USERS) return;
        emb = ie32; outb = agg_users;
        nspans = SLICES_I; binBase = N_I; binStride = NUM_USERS;
    }
    int m = lane & 31;          // uint column within emb row (2 dims)
    int h = lane >> 5;          // 0: record A, 1: record B
    float ax[GW_ROWS], ay[GW_ROWS];
#pragma unroll
    for (int j = 0; j < GW_ROWS; ++j) { ax[j] = 0.f; ay[j] = 0.f; }
    for (int sp = 0; sp < nspans; ++sp) {
        int base = binBase + sp * binStride + r0;
#pragma unroll
        for (int j = 0; j < GW_ROWS; ++j) {
            int k = off[base + j];
            int e = off[base + j + 1];
            float x = ax[j], y = ay[j];
            for (; k < e; k += 2) {
                int idx = k + h;
                uint rr = (idx < e) ? rec[idx] : 0u;   // pad: w=0 -> adds 0
                float wq = (float)(rr & 0x7FFFu) * W_INV;
                uint pk = emb[(size_t)(rr >> 15) * (DIM / 2) + m];
                x += wq * __uint_as_float(pk << 16);
                y += wq * __uint_as_float(pk & 0xFFFF0000u);
            }
            ax[j] = x; ay[j] = y;
        }
    }
#pragma unroll
    for (int j = 0; j < GW_ROWS; ++j) {
        float ox = ax[j] + __shfl_xor(ax[j], 32);
        float oy = ay[j] + __shfl_xor(ay[j], 32);
        if (lane < 32) {
            int row = r0 + j;
            float2* o2 = (float2*)(outb + (size_t)row * DIM + 2 * m);
            *o2 = make_float2(ox, oy);
        }
    }
}

// ======================= scan kernels (tier 2/3 only) =======================
__global__ __launch_bounds__(SCAN_THREADS) void scan_block_sums(
    const int* __restrict__ cnt, int* __restrict__ bsum, int n, int chunk)
{
    int b = blockIdx.x, t = threadIdx.x;
    int base = b * chunk;
    int end  = base + chunk < n ? base + chunk : n;
    int tch  = (chunk + SCAN_THREADS - 1) / SCAN_THREADS;
    int s = base + t * tch;
    int e = s + tch < end ? s + tch : end;
    int local = 0;
    for (int i = s; i < e; ++i) local += cnt[i];
    __shared__ int sm[SCAN_THREADS];
    sm[t] = local;
    __syncthreads();
    for (int o = SCAN_THREADS / 2; o > 0; o >>= 1) {
        if (t < o) sm[t] += sm[t + o];
        __syncthreads();
    }
    if (t == 0) bsum[b] = sm[0];
}

__global__ __launch_bounds__(SCAN_NB) void scan_block_offsets(
    const int* __restrict__ bsum, int* __restrict__ boff,
    int* __restrict__ off_end)
{
    int t = threadIdx.x;
    __shared__ int sm[SCAN_NB];
    int v = bsum[t];
    sm[t] = v;
    __syncthreads();
    for (int o = 1; o < SCAN_NB; o <<= 1) {
        int x = (t >= o) ? sm[t - o] : 0;
        __syncthreads();
        sm[t] += x;
        __syncthreads();
    }
    boff[t] = sm[t] - v;
    if (t == SCAN_NB - 1) *off_end = sm[SCAN_NB - 1];
}

__global__ __launch_bounds__(SCAN_THREADS) void scan_local(
    int* __restrict__ cnt, const int* __restrict__ boff, int n, int chunk)
{
    int b = blockIdx.x, t = threadIdx.x;
    int base = b * chunk;
    int end  = base + chunk < n ? base + chunk : n;
    int tch  = (chunk + SCAN_THREADS - 1) / SCAN_THREADS;
    int s = base + t * tch;
    int e = s + tch < end ? s + tch : end;
    int local = 0;
    for (int i = s; i < e; ++i) local += cnt[i];
    __shared__ int sm[SCAN_THREADS];
    sm[t] = local;
    __syncthreads();
    for (int o = 1; o < SCAN_THREADS; o <<= 1) {
        int x = (t >= o) ? sm[t - o] : 0;
        __syncthreads();
        sm[t] += x;
        __syncthreads();
    }
    int run = boff[b] + ((t == 0) ? 0 : sm[t - 1]);
    for (int i = s; i < e; ++i) {
        int c = cnt[i];
        cnt[i] = run;
        run += c;
    }
}

// ======================= exact-CSR fallback tier ============================
__global__ __launch_bounds__(256) void rank_both_exact(
    const int4* __restrict__ u4, const int4* __restrict__ i4,
    int* __restrict__ cnt, int n_i, int su_shift, int si_shift,
    int4* __restrict__ rank_i, int4* __restrict__ rank_u)
{
    int t = blockIdx.x * blockDim.x + threadIdx.x;
    if (t >= NUM_EDGES / 4) return;
    int4 u = u4[t];
    int4 i = i4[t];
    int4 ri, ru;
    ri.x = atomicAdd(&cnt[(u.x >> su_shift) * NUM_ITEMS + i.x], 1);
    ri.y = atomicAdd(&cnt[(u.y >> su_shift) * NUM_ITEMS + i.y], 1);
    ri.z = atomicAdd(&cnt[(u.z >> su_shift) * NUM_ITEMS + i.z], 1);
    ri.w = atomicAdd(&cnt[(u.w >> su_shift) * NUM_ITEMS + i.w], 1);
    ru.x = atomicAdd(&cnt[n_i + (i.x >> si_shift) * NUM_USERS + u.x], 1);
    ru.y = atomicAdd(&cnt[n_i + (i.y >> si_shift) * NUM_USERS + u.y], 1);
    ru.z = atomicAdd(&cnt[n_i + (i.z >> si_shift) * NUM_USERS + u.z], 1);
    ru.w = atomicAdd(&cnt[n_i + (i.w >> si_shift) * NUM_USERS + u.w], 1);
    rank_i[t] = ri;
    rank_u[t] = ru;
}

__global__ __launch_bounds__(256) void scatter_all(
    const int4* __restrict__ u4, const int4* __restrict__ i4,
    const float4* __restrict__ n4,
    const int4* __restrict__ rank_i, const int4* __restrict__ rank_u,
    const int* __restrict__ off, int n_i, int su_shift, int si_shift,
    uint* __restrict__ rec)
{
    int t = blockIdx.x * blockDim.x + threadIdx.x;
    if (t >= NUM_EDGES / 4) return;
    int4   u  = u4[t];
    int4   i  = i4[t];
    float4 n  = n4[t];
    int4   ri = rank_i[t];
    int4   ru = rank_u[t];
    uint w0 = (uint)(n.x * W_SCALE + 0.5f); if (w0 > 32767u) w0 = 32767u;
    uint w1 = (uint)(n.y * W_SCALE + 0.5f); if (w1 > 32767u) w1 = 32767u;
    uint w2 = (uint)(n.z * W_SCALE + 0.5f); if (w2 > 32767u) w2 = 32767u;
    uint w3 = (uint)(n.w * W_SCALE + 0.5f); if (w3 > 32767u) w3 = 32767u;
    int pi0 = off[(u.x >> su_shift) * NUM_ITEMS + i.x] + ri.x;
    int pi1 = off[(u.y >> su_shift) * NUM_ITEMS + i.y] + ri.y;
    int pi2 = off[(u.z >> su_shift) * NUM_ITEMS + i.z] + ri.z;
    int pi3 = off[(u.w >> su_shift) * NUM_ITEMS + i.w] + ri.w;
    int pu0 = off[n_i + (i.x >> si_shift) * NUM_USERS + u.x] + ru.x;
    int pu1 = off[n_i + (i.y >> si_shift) * NUM_USERS + u.y] + ru.y;
    int pu2 = off[n_i + (i.z >> si_shift) * NUM_USERS + u.z] + ru.z;
    int pu3 = off[n_i + (i.w >> si_shift) * NUM_USERS + u.w] + ru.w;
    rec[pi0] = ((uint)u.x << 15) | w0;
    rec[pi1] = ((uint)u.y << 15) | w1;
    rec[pi2] = ((uint)u.z << 15) | w2;
    rec[pi3] = ((uint)u.w << 15) | w3;
    rec[pu0] = ((uint)i.x << 15) | w0;
    rec[pu1] = ((uint)i.y << 15) | w1;
    rec[pu2] = ((uint)i.z << 15) | w2;
    rec[pu3] = ((uint)i.w << 15) | w3;
}

// ---------------- exact-CSR gather (tier 2/3 only) --------------------------
__global__ __launch_bounds__(256) void gather_pass(
    const int* __restrict__ off, int bin_base,
    const uint* __restrict__ rec,
    const ushort* __restrict__ emb16,
    float* __restrict__ out, int nrows, int accumulate)
{
    int gid  = blockIdx.x * blockDim.x + threadIdx.x;
    int row  = gid >> 6;
    int lane = gid & 63;
    if (row >= nrows) return;
    int b = bin_base + row;
    int s = off[b];
    int e = off[b + 1];
    float acc = accumulate ? out[(size_t)row * DIM + lane] : 0.f;
    int k = s;
    for (; k + 4 <= e; k += 4) {
        uint r0 = rec[k], r1 = rec[k+1], r2 = rec[k+2], r3 = rec[k+3];
        ushort b0 = emb16[(size_t)(r0 >> 15) * DIM + lane];
        ushort b1 = emb16[(size_t)(r1 >> 15) * DIM + lane];
        ushort b2 = emb16[(size_t)(r2 >> 15) * DIM + lane];
        ushort b3 = emb16[(size_t)(r3 >> 15) * DIM + lane];
        acc += (float)(r0 & 0x7FFFu) * W_INV * __uint_as_float((uint)b0 << 16);
        acc += (float)(r1 & 0x7FFFu) * W_INV * __uint_as_float((uint)b1 << 16);
        acc += (float)(r2 & 0x7FFFu) * W_INV * __uint_as_float((uint)b2 << 16);
        acc += (float)(r3 & 0x7FFFu) * W_INV * __uint_as_float((uint)b3 << 16);
    }
    for (; k < e; ++k) {
        uint r0 = rec[k];
        ushort b0 = emb16[(size_t)(r0 >> 15) * DIM + lane];
        acc += (float)(r0 & 0x7FFFu) * W_INV * __uint_as_float((uint)b0 << 16);
    }
    out[(size_t)row * DIM + lane] = acc;
}

extern "C" void kernel_launch(void* const* d_in, const int* in_sizes, int n_in,
                              void* d_out, int out_size, void* d_ws, size_t ws_size,
                              hipStream_t stream) {
    const float* user_emb  = (const float*)d_in[0];
    const float* item_emb  = (const float*)d_in[1];
    const float* edge_norm = (const float*)d_in[2];
    const int*   u_idx     = (const int*)d_in[3];
    const int*   i_idx     = (const int*)d_in[4];

    float* agg_users = (float*)d_out;                        // 100000*64
    float* agg_items = agg_users + (size_t)NUM_USERS * DIM;  // 50000*64

    const int un4 = NUM_USERS * DIM / 4;
    const int in4 = NUM_ITEMS * DIM / 4;
    const int eb4 = (NUM_EDGES / 4 + 255) / 256;
    const int cb  = (un4 + in4 + 255) / 256;
    const size_t bf16_bytes = ((size_t)NUM_USERS + NUM_ITEMS) * DIM * sizeof(ushort);

    // ---------- tier 1: deterministic bucket partition -> local-scan CSR ----
    {
        const size_t off_bytes  = (size_t)(N_TOTAL + 1) * sizeof(int);
        const size_t buk_bytes  = (size_t)(2 * NBUK + 2) * sizeof(int);
        const size_t wgh_bytes  = (size_t)PWG * NBUK * sizeof(ushort);     // 1.4 MB
        const size_t wgp_bytes  = (size_t)NBUK * PWG * sizeof(uint);       // 2.9 MB
        const size_t prec_bytes = (size_t)2 * NUM_EDGES * sizeof(uint);    // 32 MB
        const size_t pbin_bytes = (size_t)2 * NUM_EDGES * sizeof(ushort);  // 16 MB
        const size_t rec_bytes  = (size_t)2 * NUM_EDGES * sizeof(uint);    // 32 MB
        const size_t need = off_bytes + buk_bytes + 64 + wgh_bytes + 64
                          + wgp_bytes + 64 + prec_bytes + 64 + pbin_bytes + 64
                          + rec_bytes + 64 + bf16_bytes + 256;
        if (ws_size >= need) {
            char* p = (char*)d_ws;
            int*    off     = (int*)p;    p += off_bytes;
            int*    bukTot  = (int*)p;    p += (size_t)NBUK * sizeof(int);
            int*    bukOff  = (int*)p;    p += (size_t)(NBUK + 1) * sizeof(int);
            p = (char*)(((uintptr_t)p + 63) & ~(uintptr_t)63);
            ushort* wgHist  = (ushort*)p; p += wgh_bytes;
            p = (char*)(((uintptr_t)p + 63) & ~(uintptr_t)63);
            uint*   wgPrefixT = (uint*)p; p += wgp_bytes;
            p = (char*)(((uintptr_t)p + 63) & ~(uintptr_t)63);
            uint*   pairRec = (uint*)p;   p += prec_bytes;
            p = (char*)(((uintptr_t)p + 63) & ~(uintptr_t)63);
            ushort* pairBin = (ushort*)p; p += pbin_bytes;
            p = (char*)(((uintptr_t)p + 63) & ~(uintptr_t)63);
            uint*   rec     = (uint*)p;   p += rec_bytes;
            p = (char*)(((uintptr_t)p + 63) & ~(uintptr_t)63);
            ushort* ue16    = (ushort*)p; p += (size_t)NUM_USERS * DIM * sizeof(ushort);
            ushort* ie16    = (ushort*)p;

            bucket_hist_conv<<<PWG + cb, 256, 0, stream>>>(
                u_idx, i_idx, wgHist,
                (const float4*)user_emb, (const float4*)item_emb,
                (ushort4*)ue16, (ushort4*)ie16, un4, in4, PWG);
            mscan<<<NBUK, 256, 0, stream>>>(wgHist, wgPrefixT, bukTot);
            bucket_scan<<<1, 256, 0, stream>>>(bukTot, bukOff, off + N_TOTAL);
            partition_pairs<<<PWG, 256, 0, stream>>>(
                u_idx, i_idx, edge_norm, wgHist, wgPrefixT, bukOff,
                pairRec, pairBin);
            bucket_fill<<<NBUK, BF_THREADS, 0, stream>>>(
                bukOff, pairRec, pairBin, off, rec);
            // merged phase-major gather, both directions, one launch
            const int gwaves = NUM_ITEMS / GW_ROWS + NUM_USERS / GW_ROWS; // 18750
            const int gblocks = (gwaves * 64 + 255) / 256;
            gather_pm<<<gblocks, 256, 0, stream>>>(
                off, rec, (const uint*)ue16, (const uint*)ie16,
                agg_users, agg_items);
            return;
        }
    }

    // ---------- tier 2/3: exact CSR via global atomics, sliced or not -------
    {
        const size_t rec_bytes  = (size_t)2 * NUM_EDGES * sizeof(uint);
        const size_t rank_bytes = (size_t)2 * NUM_EDGES * sizeof(int);
        auto need_for = [&](int SU, int SI) -> size_t {
            size_t n_total = (size_t)SU * NUM_ITEMS + (size_t)SI * NUM_USERS;
            size_t off_bytes = (n_total + 1 + 2 * SCAN_NB) * sizeof(int);
            return off_bytes + 64 + rec_bytes + 64 + rank_bytes + 64 + bf16_bytes
                 + 256;
        };
        int SU = 0, SI = 0, su_shift = 17, si_shift = 17;
        if (ws_size >= need_for(SLICES_U, SLICES_I)) {
            SU = SLICES_U; SI = SLICES_I;
            su_shift = SLICE_SHIFT; si_shift = SLICE_SHIFT;
        } else if (ws_size >= need_for(1, 1)) {
            SU = 1; SI = 1;
        }
        if (SU > 0) {
            const int n_i = SU * NUM_ITEMS;
            const int n_u = SI * NUM_USERS;
            const int n_total = n_i + n_u;

            char* p = (char*)d_ws;
            int*   cnt  = (int*)p;   p += (size_t)(n_total + 1) * sizeof(int);
            int*   bsum = (int*)p;   p += (size_t)SCAN_NB * sizeof(int);
            int*   boff = (int*)p;   p += (size_t)SCAN_NB * sizeof(int);
            p = (char*)(((uintptr_t)p + 63) & ~(uintptr_t)63);
            uint*  rec  = (uint*)p;  p += rec_bytes;
            p = (char*)(((uintptr_t)p + 63) & ~(uintptr_t)63);
            int*   rank_i = (int*)p; p += (size_t)NUM_EDGES * sizeof(int);
            int*   rank_u = (int*)p; p += (size_t)NUM_EDGES * sizeof(int);
            p = (char*)(((uintptr_t)p + 63) & ~(uintptr_t)63);
            ushort* ue16 = (ushort*)p; p += (size_t)NUM_USERS * DIM * sizeof(ushort);
            ushort* ie16 = (ushort*)p;

            hipMemsetAsync(cnt, 0, (size_t)(n_total + 1) * sizeof(int), stream);
            convert_both<<<cb, 256, 0, stream>>>(
                (const float4*)user_emb, (const float4*)item_emb,
                (ushort4*)ue16, (ushort4*)ie16, un4, in4);
            rank_both_exact<<<eb4, 256, 0, stream>>>(
                (const int4*)u_idx, (const int4*)i_idx, cnt, n_i,
                su_shift, si_shift, (int4*)rank_i, (int4*)rank_u);
            const int chunk = (n_total + SCAN_NB - 1) / SCAN_NB;
            scan_block_sums<<<SCAN_NB, SCAN_THREADS, 0, stream>>>(
                cnt, bsum, n_total, chunk);
            scan_block_offsets<<<1, SCAN_NB, 0, stream>>>(bsum, boff, cnt + n_total);
            scan_local<<<SCAN_NB, SCAN_THREADS, 0, stream>>>(
                cnt, boff, n_total, chunk);
            scatter_all<<<eb4, 256, 0, stream>>>(
                (const int4*)u_idx, (const int4*)i_idx, (const float4*)edge_norm,
                (const int4*)rank_i, (const int4*)rank_u,
                cnt, n_i, su_shift, si_shift, rec);
            for (int s = 0; s < SU; ++s) {
                gather_pass<<<((NUM_ITEMS * 64) + 255) / 256, 256, 0, stream>>>(
                    cnt, s * NUM_ITEMS, rec, ue16, agg_items, NUM_ITEMS,
                    s > 0 ? 1 : 0);
            }
            for (int s = 0; s < SI; ++s) {
                gather_pass<<<((NUM_USERS * 64) + 255) / 256, 256, 0, stream>>>(
                    cnt, n_i + s * NUM_USERS, rec, ie16, agg_users, NUM_USERS,
                    s > 0 ? 1 : 0);
            }
            return;
        }
    }

    // ---------- tier 4: scatter-atomic ----------
    hipMemsetAsync(d_out, 0, (size_t)out_size * sizeof(float), stream);
    const long long total_threads = (long long)NUM_EDGES * 64;
    const int blocks = (int)((total_threads + 255) / 256);
    lightgcn_scatter<<<blocks, 256, 0, stream>>>(
        user_emb, item_emb, edge_norm, u_idx, i_idx, agg_users, agg_items);
}

// Round 10
// 394.723 us; speedup vs baseline: 1.5721x; 1.5721x over previous
//
#include <hip/hip_runtime.h>

#define NUM_USERS 100000
#define NUM_ITEMS 50000
#define NUM_EDGES 4000000
#define DIM 64

// Source-table slicing: 1<<14 = 16384 rows/slice = 2 MB bf16 per slice
// (phase-major gather holds one slice per direction in L2; 2+2 MB = L2).
#define SLICE_SHIFT 14
#define SLICES_U ((NUM_USERS + (1 << SLICE_SHIFT) - 1) >> SLICE_SHIFT)  // 7
#define SLICES_I ((NUM_ITEMS + (1 << SLICE_SHIFT) - 1) >> SLICE_SHIFT)  // 4

#define N_I (SLICES_U * NUM_ITEMS)   // 350000 item-direction bins
#define N_U (SLICES_I * NUM_USERS)   // 400000 user-direction bins
#define N_TOTAL (N_I + N_U)          // 750000

#define SCAN_NB 512
#define SCAN_THREADS 256

// ---- two-level bucket partition --------------------------------------------
#define PCHUNK 4096                    // edges per partition workgroup
#define PWG ((NUM_EDGES + PCHUNK - 1) / PCHUNK)   // 977
#define BUK_SHIFT 10                   // 1024 bins per bucket
#define BUK_BINS (1 << BUK_SHIFT)
#define NBUK_I ((N_I + BUK_BINS - 1) >> BUK_SHIFT)   // 342
#define NBUK_U ((N_U + BUK_BINS - 1) >> BUK_SHIFT)   // 391
#define NBUK (NBUK_I + NBUK_U)                       // 733

#define STAGE_CAP 15360
#define BF_THREADS 512

// Gather: each wave owns 8 contiguous rows; merged directions; paired records.
#define GW_ROWS 8

// Packed CSR record: (src_row << 15) | w_quant15 (err <= 1.5e-5 << bf16 noise).
#define W_SCALE 32767.0f
#define W_INV   (1.0f / 32767.0f)

// ---------------- fallback: scatter-atomic (round-1 kernel) ----------------
__global__ __launch_bounds__(256) void lightgcn_scatter(
    const float* __restrict__ user_emb,
    const float* __restrict__ item_emb,
    const float* __restrict__ edge_norm,
    const int* __restrict__ u_idx,
    const int* __restrict__ i_idx,
    float* __restrict__ agg_users,
    float* __restrict__ agg_items)
{
    long long gid = (long long)blockIdx.x * blockDim.x + threadIdx.x;
    int edge = (int)(gid >> 6);
    int lane = (int)(gid & 63);
    if (edge >= NUM_EDGES) return;
    int u = u_idx[edge];
    int i = i_idx[edge];
    float n = edge_norm[edge];
    float uval = user_emb[(size_t)u * DIM + lane];
    float ival = item_emb[(size_t)i * DIM + lane];
    atomicAdd(&agg_items[(size_t)i * DIM + lane], n * uval);
    atomicAdd(&agg_users[(size_t)u * DIM + lane], n * ival);
}

// ---------------- bf16 conversion of BOTH embedding tables -----------------
__global__ __launch_bounds__(256) void convert_both(
    const float4* __restrict__ usrc, const float4* __restrict__ isrc,
    ushort4* __restrict__ udst, ushort4* __restrict__ idst,
    int un4, int in4)
{
    int t = blockIdx.x * blockDim.x + threadIdx.x;
    const float4* s; ushort4* d; int idx;
    if (t < un4) { s = usrc; d = udst; idx = t; }
    else if (t < un4 + in4) { s = isrc; d = idst; idx = t - un4; }
    else return;
    float4 v = s[idx];
    ushort4 o;
    uint b;
    b = __float_as_uint(v.x); o.x = (ushort)((b + 0x7FFFu + ((b >> 16) & 1u)) >> 16);
    b = __float_as_uint(v.y); o.y = (ushort)((b + 0x7FFFu + ((b >> 16) & 1u)) >> 16);
    b = __float_as_uint(v.z); o.z = (ushort)((b + 0x7FFFu + ((b >> 16) & 1u)) >> 16);
    b = __float_as_uint(v.w); o.w = (ushort)((b + 0x7FFFu + ((b >> 16) & 1u)) >> 16);
    d[idx] = o;
}

// ---------------- phase A: per-WG bucket histograms (+ convert folded) ------
__global__ __launch_bounds__(256) void bucket_hist_conv(
    const int* __restrict__ u_idx, const int* __restrict__ i_idx,
    ushort* __restrict__ wgHist,
    const float4* __restrict__ usrc, const float4* __restrict__ isrc,
    ushort4* __restrict__ udst, ushort4* __restrict__ idst,
    int un4, int in4, int hist_blocks)
{
    __shared__ uint hist[NBUK];
    if ((int)blockIdx.x >= hist_blocks) {
        int ct = (blockIdx.x - hist_blocks) * blockDim.x + threadIdx.x;
        const float4* s; ushort4* d; int idx;
        if (ct < un4) { s = usrc; d = udst; idx = ct; }
        else if (ct < un4 + in4) { s = isrc; d = idst; idx = ct - un4; }
        else return;
        float4 v = s[idx];
        ushort4 o;
        uint b;
        b = __float_as_uint(v.x); o.x = (ushort)((b + 0x7FFFu + ((b >> 16) & 1u)) >> 16);
        b = __float_as_uint(v.y); o.y = (ushort)((b + 0x7FFFu + ((b >> 16) & 1u)) >> 16);
        b = __float_as_uint(v.z); o.z = (ushort)((b + 0x7FFFu + ((b >> 16) & 1u)) >> 16);
        b = __float_as_uint(v.w); o.w = (ushort)((b + 0x7FFFu + ((b >> 16) & 1u)) >> 16);
        d[idx] = o;
        return;
    }
    int t = threadIdx.x;
    for (int b = t; b < NBUK; b += 256) hist[b] = 0;
    __syncthreads();
    int e0 = blockIdx.x * PCHUNK;
    int ecnt = NUM_EDGES - e0; if (ecnt > PCHUNK) ecnt = PCHUNK;
    for (int k = t; k < ecnt; k += 256) {
        int u = u_idx[e0 + k];
        int i = i_idx[e0 + k];
        atomicAdd(&hist[((u >> SLICE_SHIFT) * NUM_ITEMS + i) >> BUK_SHIFT], 1u);
        atomicAdd(&hist[NBUK_I + (((i >> SLICE_SHIFT) * NUM_USERS + u) >> BUK_SHIFT)], 1u);
    }
    __syncthreads();
    ushort* row = wgHist + (size_t)blockIdx.x * NBUK;
    for (int b = t; b < NBUK; b += 256) row[b] = (ushort)hist[b];
}

// ---------------- phase B1: per-bucket scan over WGs (no atomics) -----------
__global__ __launch_bounds__(256) void mscan(
    const ushort* __restrict__ wgHist, uint* __restrict__ wgPrefixT,
    int* __restrict__ bukTot)
{
    __shared__ uint sm[256];
    int b = blockIdx.x, t = threadIdx.x;
    int i0 = t * 4;
    uint c0 = 0, c1 = 0, c2 = 0, c3 = 0;
    if (i0 + 0 < PWG) c0 = wgHist[(size_t)(i0 + 0) * NBUK + b];
    if (i0 + 1 < PWG) c1 = wgHist[(size_t)(i0 + 1) * NBUK + b];
    if (i0 + 2 < PWG) c2 = wgHist[(size_t)(i0 + 2) * NBUK + b];
    if (i0 + 3 < PWG) c3 = wgHist[(size_t)(i0 + 3) * NBUK + b];
    sm[t] = c0 + c1 + c2 + c3;
    __syncthreads();
    for (int o = 1; o < 256; o <<= 1) {
        uint x = (t >= o) ? sm[t - o] : 0;
        __syncthreads();
        sm[t] += x;
        __syncthreads();
    }
    uint excl = (t == 0) ? 0u : sm[t - 1];
    uint* orow = wgPrefixT + (size_t)b * PWG;
    if (i0 + 0 < PWG) orow[i0 + 0] = excl;
    if (i0 + 1 < PWG) orow[i0 + 1] = excl + c0;
    if (i0 + 2 < PWG) orow[i0 + 2] = excl + c0 + c1;
    if (i0 + 3 < PWG) orow[i0 + 3] = excl + c0 + c1 + c2;
    if (t == 255) bukTot[b] = (int)sm[255];
}

// ---------------- phase B2: scan 733 bucket totals (single WG) --------------
__global__ __launch_bounds__(256) void bucket_scan(
    const int* __restrict__ bukTot, int* __restrict__ bukOff,
    int* __restrict__ off_last)
{
    __shared__ int sm[256];
    int t = threadIdx.x;
    int b4 = t * 4;
    int v0 = 0, v1 = 0, v2 = 0, v3 = 0;
    if (b4 + 0 < NBUK) v0 = bukTot[b4 + 0];
    if (b4 + 1 < NBUK) v1 = bukTot[b4 + 1];
    if (b4 + 2 < NBUK) v2 = bukTot[b4 + 2];
    if (b4 + 3 < NBUK) v3 = bukTot[b4 + 3];
    sm[t] = v0 + v1 + v2 + v3;
    __syncthreads();
    for (int o = 1; o < 256; o <<= 1) {
        int x = (t >= o) ? sm[t - o] : 0;
        __syncthreads();
        sm[t] += x;
        __syncthreads();
    }
    int excl = (t == 0) ? 0 : sm[t - 1];
    if (b4 + 0 < NBUK) bukOff[b4 + 0] = excl;
    if (b4 + 1 < NBUK) bukOff[b4 + 1] = excl + v0;
    if (b4 + 2 < NBUK) bukOff[b4 + 2] = excl + v0 + v1;
    if (b4 + 3 < NBUK) bukOff[b4 + 3] = excl + v0 + v1 + v2;
    if (t == 255) bukOff[NBUK] = sm[255];
    if (t == 0) *off_last = 2 * NUM_EDGES;   // off[N_TOTAL]
}

// ---------------- phase C: per-WG LDS counting-sort into exact slabs --------
__global__ __launch_bounds__(256) void partition_pairs(
    const int* __restrict__ u_idx, const int* __restrict__ i_idx,
    const float* __restrict__ edge_norm,
    const ushort* __restrict__ wgHist, const uint* __restrict__ wgPrefixT,
    const int* __restrict__ bukOff,
    uint* __restrict__ pairRec, ushort* __restrict__ pairBin)
{
    __shared__ uint recS[2 * PCHUNK];   // 32 KB packed records, bucket-sorted
    __shared__ uint bbS[2 * PCHUNK];    // 32 KB (buk<<BUK_SHIFT)|lbin per slot
    __shared__ uint hist[NBUK];
    __shared__ uint cursor[NBUK];
    __shared__ uint gbase[NBUK];
    __shared__ uint scanTmp[256];

    int t  = threadIdx.x;
    int wg = blockIdx.x;
    int e0 = wg * PCHUNK;
    int ecnt = NUM_EDGES - e0; if (ecnt > PCHUNK) ecnt = PCHUNK;

    const ushort* hrow = wgHist + (size_t)wg * NBUK;
    for (int b = t; b < NBUK; b += 256) {
        hist[b]  = hrow[b];
        gbase[b] = (uint)bukOff[b] + wgPrefixT[(size_t)b * PWG + wg];
    }
    __syncthreads();

    // exclusive scan hist -> cursor
    int base4 = t * 4;
    uint v0 = 0, v1 = 0, v2 = 0, v3 = 0;
    if (base4 + 0 < NBUK) v0 = hist[base4 + 0];
    if (base4 + 1 < NBUK) v1 = hist[base4 + 1];
    if (base4 + 2 < NBUK) v2 = hist[base4 + 2];
    if (base4 + 3 < NBUK) v3 = hist[base4 + 3];
    scanTmp[t] = v0 + v1 + v2 + v3;
    __syncthreads();
    for (int o = 1; o < 256; o <<= 1) {
        uint x = (t >= o) ? scanTmp[t - o] : 0;
        __syncthreads();
        scanTmp[t] += x;
        __syncthreads();
    }
    uint excl = (t == 0) ? 0u : scanTmp[t - 1];
    if (base4 + 0 < NBUK) cursor[base4 + 0] = excl;
    if (base4 + 1 < NBUK) cursor[base4 + 1] = excl + v0;
    if (base4 + 2 < NBUK) cursor[base4 + 2] = excl + v0 + v1;
    if (base4 + 3 < NBUK) cursor[base4 + 3] = excl + v0 + v1 + v2;
    __syncthreads();

    // stage pairs into bucket-sorted LDS order
    for (int k = t; k < ecnt; k += 256) {
        int u = u_idx[e0 + k];
        int i = i_idx[e0 + k];
        float n = edge_norm[e0 + k];
        uint w = (uint)(n * W_SCALE + 0.5f); if (w > 32767u) w = 32767u;
        int binI = (u >> SLICE_SHIFT) * NUM_ITEMS + i;
        int binU = (i >> SLICE_SHIFT) * NUM_USERS + u;
        uint bI = (uint)(binI >> BUK_SHIFT);
        uint bU = (uint)(NBUK_I + (binU >> BUK_SHIFT));
        uint rI = atomicAdd(&cursor[bI], 1u);
        recS[rI] = ((uint)u << 15) | w;
        bbS[rI]  = (bI << BUK_SHIFT) | (uint)(binI & (BUK_BINS - 1));
        uint rU = atomicAdd(&cursor[bU], 1u);
        recS[rU] = ((uint)i << 15) | w;
        bbS[rU]  = (bU << BUK_SHIFT) | (uint)(binU & (BUK_BINS - 1));
    }
    __syncthreads();

    // write out sorted slots; consecutive slots -> consecutive global addrs
    int total = 2 * ecnt;
    for (int s = t; s < total; s += 256) {
        uint bb = bbS[s];
        uint b  = bb >> BUK_SHIFT;
        uint wb = cursor[b] - hist[b];           // bucket's local base in LDS
        uint lpos = gbase[b] + ((uint)s - wb);   // exact: always in range
        pairRec[lpos] = recS[s];
        pairBin[lpos] = (ushort)(bb & (BUK_BINS - 1));
    }
}

// ---------------- phase D: per-bucket CSR offsets + LDS-staged placement ----
__global__ __launch_bounds__(BF_THREADS) void bucket_fill(
    const int* __restrict__ bukOff,
    const uint* __restrict__ pairRec, const ushort* __restrict__ pairBin,
    int* __restrict__ off, uint* __restrict__ rec)
{
    __shared__ uint recS[STAGE_CAP];      // 60 KB
    __shared__ uint lcnt[BUK_BINS];       // 4 KB
    __shared__ uint cur[BUK_BINS];        // 4 KB
    __shared__ uint scanSm[BF_THREADS];   // 2 KB
    int b = blockIdx.x, t = threadIdx.x;
    lcnt[t] = 0; lcnt[t + BF_THREADS] = 0;
    __syncthreads();
    int s0 = bukOff[b], s1 = bukOff[b + 1];
    int n = s1 - s0;
    for (int k = t; k < n; k += BF_THREADS)
        atomicAdd(&lcnt[pairBin[s0 + k]], 1u);
    __syncthreads();
    // exclusive scan of 1024 counts, 2 per thread
    uint a0 = lcnt[2 * t], a1 = lcnt[2 * t + 1];
    scanSm[t] = a0 + a1;
    __syncthreads();
    for (int o = 1; o < BF_THREADS; o <<= 1) {
        uint x = (t >= o) ? scanSm[t - o] : 0;
        __syncthreads();
        scanSm[t] += x;
        __syncthreads();
    }
    uint excl = scanSm[t] - (a0 + a1);
    cur[2 * t]     = excl;
    cur[2 * t + 1] = excl + a0;
    // write CSR offsets for this bucket's real bins
    int gbin0, dirEnd;
    if (b < NBUK_I) { gbin0 = b << BUK_SHIFT; dirEnd = N_I; }
    else { gbin0 = N_I + ((b - NBUK_I) << BUK_SHIFT); dirEnd = N_TOTAL; }
    int lim = dirEnd - gbin0; if (lim > BUK_BINS) lim = BUK_BINS;
    if (2 * t     < lim) off[gbin0 + 2 * t]     = s0 + (int)excl;
    if (2 * t + 1 < lim) off[gbin0 + 2 * t + 1] = s0 + (int)(excl + a0);
    __syncthreads();   // cur[] visible before placement mutates it
    if (n <= STAGE_CAP) {
        for (int k = t; k < n; k += BF_THREADS) {
            uint lbin = pairBin[s0 + k];
            uint r = atomicAdd(&cur[lbin], 1u);
            recS[r] = pairRec[s0 + k];
        }
        __syncthreads();
        for (int k = t; k < n; k += BF_THREADS)   // linear, fully-coalesced
            rec[(size_t)s0 + k] = recS[k];
    } else {
        // exact fallback (never expected at this data scale)
        for (int k = t; k < n; k += BF_THREADS) {
            uint lbin = pairBin[s0 + k];
            uint r = atomicAdd(&cur[lbin], 1u);
            rec[(size_t)s0 + r] = pairRec[s0 + k];
        }
    }
}

// ---------------- phase E: merged phase-major gather, paired + unrolled -----
// Round-10. Round-9's paired loop fixed occupancy (74%) and locality
// (FETCH 191 MB) but serialized the rec->emb dependency chain (VALU 29%,
// 398 us: MLP ~1). This version keeps the paired half-wave scheme (2 records
// per wave-step, ~7 wave-instrs/record) and restores round-6's MLP:
//  - main loop unrolled x4: 4 independent rec loads, then 4 independent
//    emb loads in flight (8 records per iteration);
//  - tail handled by ONE masked batch (guarded loads, w=0 pads) instead of
//    a serial pair loop -- short spans (avg ~11) = 2 pipelined iterations;
//  - the span's 9 CSR offsets come from one coalesced load + __shfl,
//    removing 16 serialized scalar loads per span.
__global__ __launch_bounds__(256) void gather_pm(
    const int* __restrict__ off, const uint* __restrict__ rec,
    const uint* __restrict__ ue32, const uint* __restrict__ ie32,
    float* __restrict__ agg_users, float* __restrict__ agg_items)
{
    int wid  = (blockIdx.x * blockDim.x + threadIdx.x) >> 6;
    int lane = threadIdx.x & 63;
    const int IW = NUM_ITEMS / GW_ROWS;          // 6250 item-direction waves
    const uint* emb; float* outb; int r0, nspans, binBase, binStride;
    if (wid < IW) {
        r0 = wid * GW_ROWS;
        emb = ue32; outb = agg_items;
        nspans = SLICES_U; binBase = 0; binStride = NUM_ITEMS;
    } else {
        r0 = (wid - IW) * GW_ROWS;
        if (r0 >= NUM_USERS) return;
        emb = ie32; outb = agg_users;
        nspans = SLICES_I; binBase = N_I; binStride = NUM_USERS;
    }
    int m = lane & 31;          // uint column within emb row (2 dims)
    int h = lane >> 5;          // 0: even records, 1: odd records
    float ax[GW_ROWS], ay[GW_ROWS];
#pragma unroll
    for (int j = 0; j < GW_ROWS; ++j) { ax[j] = 0.f; ay[j] = 0.f; }
    for (int sp = 0; sp < nspans; ++sp) {
        int base = binBase + sp * binStride + r0;
        // one coalesced load serves all 9 offsets of this span
        int ov = (lane <= GW_ROWS) ? off[base + lane] : 0;
#pragma unroll
        for (int j = 0; j < GW_ROWS; ++j) {
            int k = __shfl(ov, j);
            int e = __shfl(ov, j + 1);
            float x = ax[j], y = ay[j];
            for (; k + 8 <= e; k += 8) {
                uint rr0 = rec[k + 0 + h];
                uint rr1 = rec[k + 2 + h];
                uint rr2 = rec[k + 4 + h];
                uint rr3 = rec[k + 6 + h];
                uint pk0 = emb[(size_t)(rr0 >> 15) * (DIM / 2) + m];
                uint pk1 = emb[(size_t)(rr1 >> 15) * (DIM / 2) + m];
                uint pk2 = emb[(size_t)(rr2 >> 15) * (DIM / 2) + m];
                uint pk3 = emb[(size_t)(rr3 >> 15) * (DIM / 2) + m];
                float w0 = (float)(rr0 & 0x7FFFu) * W_INV;
                float w1 = (float)(rr1 & 0x7FFFu) * W_INV;
                float w2 = (float)(rr2 & 0x7FFFu) * W_INV;
                float w3 = (float)(rr3 & 0x7FFFu) * W_INV;
                x += w0 * __uint_as_float(pk0 << 16);
                y += w0 * __uint_as_float(pk0 & 0xFFFF0000u);
                x += w1 * __uint_as_float(pk1 << 16);
                y += w1 * __uint_as_float(pk1 & 0xFFFF0000u);
                x += w2 * __uint_as_float(pk2 << 16);
                y += w2 * __uint_as_float(pk2 & 0xFFFF0000u);
                x += w3 * __uint_as_float(pk3 << 16);
                y += w3 * __uint_as_float(pk3 & 0xFFFF0000u);
            }
            if (k < e) {
                int i0 = k + 0 + h, i1 = k + 2 + h, i2 = k + 4 + h, i3 = k + 6 + h;
                uint rr0 = (i0 < e) ? rec[i0] : 0u;   // pad: w=0 -> adds 0
                uint rr1 = (i1 < e) ? rec[i1] : 0u;
                uint rr2 = (i2 < e) ? rec[i2] : 0u;
                uint rr3 = (i3 < e) ? rec[i3] : 0u;
                uint pk0 = emb[(size_t)(rr0 >> 15) * (DIM / 2) + m];
                uint pk1 = emb[(size_t)(rr1 >> 15) * (DIM / 2) + m];
                uint pk2 = emb[(size_t)(rr2 >> 15) * (DIM / 2) + m];
                uint pk3 = emb[(size_t)(rr3 >> 15) * (DIM / 2) + m];
                float w0 = (float)(rr0 & 0x7FFFu) * W_INV;
                float w1 = (float)(rr1 & 0x7FFFu) * W_INV;
                float w2 = (float)(rr2 & 0x7FFFu) * W_INV;
                float w3 = (float)(rr3 & 0x7FFFu) * W_INV;
                x += w0 * __uint_as_float(pk0 << 16);
                y += w0 * __uint_as_float(pk0 & 0xFFFF0000u);
                x += w1 * __uint_as_float(pk1 << 16);
                y += w1 * __uint_as_float(pk1 & 0xFFFF0000u);
                x += w2 * __uint_as_float(pk2 << 16);
                y += w2 * __uint_as_float(pk2 & 0xFFFF0000u);
                x += w3 * __uint_as_float(pk3 << 16);
                y += w3 * __uint_as_float(pk3 & 0xFFFF0000u);
            }
            ax[j] = x; ay[j] = y;
        }
    }
#pragma unroll
    for (int j = 0; j < GW_ROWS; ++j) {
        float ox = ax[j] + __shfl_xor(ax[j], 32);
        float oy = ay[j] + __shfl_xor(ay[j], 32);
        if (lane < 32) {
            int row = r0 + j;
            float2* o2 = (float2*)(outb + (size_t)row * DIM + 2 * m);
            *o2 = make_float2(ox, oy);
        }
    }
}

// ======================= scan kernels (tier 2/3 only) =======================
__global__ __launch_bounds__(SCAN_THREADS) void scan_block_sums(
    const int* __restrict__ cnt, int* __restrict__ bsum, int n, int chunk)
{
    int b = blockIdx.x, t = threadIdx.x;
    int base = b * chunk;
    int end  = base + chunk < n ? base + chunk : n;
    int tch  = (chunk + SCAN_THREADS - 1) / SCAN_THREADS;
    int s = base + t * tch;
    int e = s + tch < end ? s + tch : end;
    int local = 0;
    for (int i = s; i < e; ++i) local += cnt[i];
    __shared__ int sm[SCAN_THREADS];
    sm[t] = local;
    __syncthreads();
    for (int o = SCAN_THREADS / 2; o > 0; o >>= 1) {
        if (t < o) sm[t] += sm[t + o];
        __syncthreads();
    }
    if (t == 0) bsum[b] = sm[0];
}

__global__ __launch_bounds__(SCAN_NB) void scan_block_offsets(
    const int* __restrict__ bsum, int* __restrict__ boff,
    int* __restrict__ off_end)
{
    int t = threadIdx.x;
    __shared__ int sm[SCAN_NB];
    int v = bsum[t];
    sm[t] = v;
    __syncthreads();
    for (int o = 1; o < SCAN_NB; o <<= 1) {
        int x = (t >= o) ? sm[t - o] : 0;
        __syncthreads();
        sm[t] += x;
        __syncthreads();
    }
    boff[t] = sm[t] - v;
    if (t == SCAN_NB - 1) *off_end = sm[SCAN_NB - 1];
}

__global__ __launch_bounds__(SCAN_THREADS) void scan_local(
    int* __restrict__ cnt, const int* __restrict__ boff, int n, int chunk)
{
    int b = blockIdx.x, t = threadIdx.x;
    int base = b * chunk;
    int end  = base + chunk < n ? base + chunk : n;
    int tch  = (chunk + SCAN_THREADS - 1) / SCAN_THREADS;
    int s = base + t * tch;
    int e = s + tch < end ? s + tch : end;
    int local = 0;
    for (int i = s; i < e; ++i) local += cnt[i];
    __shared__ int sm[SCAN_THREADS];
    sm[t] = local;
    __syncthreads();
    for (int o = 1; o < SCAN_THREADS; o <<= 1) {
        int x = (t >= o) ? sm[t - o] : 0;
        __syncthreads();
        sm[t] += x;
        __syncthreads();
    }
    int run = boff[b] + ((t == 0) ? 0 : sm[t - 1]);
    for (int i = s; i < e; ++i) {
        int c = cnt[i];
        cnt[i] = run;
        run += c;
    }
}

// ======================= exact-CSR fallback tier ============================
__global__ __launch_bounds__(256) void rank_both_exact(
    const int4* __restrict__ u4, const int4* __restrict__ i4,
    int* __restrict__ cnt, int n_i, int su_shift, int si_shift,
    int4* __restrict__ rank_i, int4* __restrict__ rank_u)
{
    int t = blockIdx.x * blockDim.x + threadIdx.x;
    if (t >= NUM_EDGES / 4) return;
    int4 u = u4[t];
    int4 i = i4[t];
    int4 ri, ru;
    ri.x = atomicAdd(&cnt[(u.x >> su_shift) * NUM_ITEMS + i.x], 1);
    ri.y = atomicAdd(&cnt[(u.y >> su_shift) * NUM_ITEMS + i.y], 1);
    ri.z = atomicAdd(&cnt[(u.z >> su_shift) * NUM_ITEMS + i.z], 1);
    ri.w = atomicAdd(&cnt[(u.w >> su_shift) * NUM_ITEMS + i.w], 1);
    ru.x = atomicAdd(&cnt[n_i + (i.x >> si_shift) * NUM_USERS + u.x], 1);
    ru.y = atomicAdd(&cnt[n_i + (i.y >> si_shift) * NUM_USERS + u.y], 1);
    ru.z = atomicAdd(&cnt[n_i + (i.z >> si_shift) * NUM_USERS + u.z], 1);
    ru.w = atomicAdd(&cnt[n_i + (i.w >> si_shift) * NUM_USERS + u.w], 1);
    rank_i[t] = ri;
    rank_u[t] = ru;
}

__global__ __launch_bounds__(256) void scatter_all(
    const int4* __restrict__ u4, const int4* __restrict__ i4,
    const float4* __restrict__ n4,
    const int4* __restrict__ rank_i, const int4* __restrict__ rank_u,
    const int* __restrict__ off, int n_i, int su_shift, int si_shift,
    uint* __restrict__ rec)
{
    int t = blockIdx.x * blockDim.x + threadIdx.x;
    if (t >= NUM_EDGES / 4) return;
    int4   u  = u4[t];
    int4   i  = i4[t];
    float4 n  = n4[t];
    int4   ri = rank_i[t];
    int4   ru = rank_u[t];
    uint w0 = (uint)(n.x * W_SCALE + 0.5f); if (w0 > 32767u) w0 = 32767u;
    uint w1 = (uint)(n.y * W_SCALE + 0.5f); if (w1 > 32767u) w1 = 32767u;
    uint w2 = (uint)(n.z * W_SCALE + 0.5f); if (w2 > 32767u) w2 = 32767u;
    uint w3 = (uint)(n.w * W_SCALE + 0.5f); if (w3 > 32767u) w3 = 32767u;
    int pi0 = off[(u.x >> su_shift) * NUM_ITEMS + i.x] + ri.x;
    int pi1 = off[(u.y >> su_shift) * NUM_ITEMS + i.y] + ri.y;
    int pi2 = off[(u.z >> su_shift) * NUM_ITEMS + i.z] + ri.z;
    int pi3 = off[(u.w >> su_shift) * NUM_ITEMS + i.w] + ri.w;
    int pu0 = off[n_i + (i.x >> si_shift) * NUM_USERS + u.x] + ru.x;
    int pu1 = off[n_i + (i.y >> si_shift) * NUM_USERS + u.y] + ru.y;
    int pu2 = off[n_i + (i.z >> si_shift) * NUM_USERS + u.z] + ru.z;
    int pu3 = off[n_i + (i.w >> si_shift) * NUM_USERS + u.w] + ru.w;
    rec[pi0] = ((uint)u.x << 15) | w0;
    rec[pi1] = ((uint)u.y << 15) | w1;
    rec[pi2] = ((uint)u.z << 15) | w2;
    rec[pi3] = ((uint)u.w << 15) | w3;
    rec[pu0] = ((uint)i.x << 15) | w0;
    rec[pu1] = ((uint)i.y << 15) | w1;
    rec[pu2] = ((uint)i.z << 15) | w2;
    rec[pu3] = ((uint)i.w << 15) | w3;
}

// ---------------- exact-CSR gather (tier 2/3 only) --------------------------
__global__ __launch_bounds__(256) void gather_pass(
    const int* __restrict__ off, int bin_base,
    const uint* __restrict__ rec,
    const ushort* __restrict__ emb16,
    float* __restrict__ out, int nrows, int accumulate)
{
    int gid  = blockIdx.x * blockDim.x + threadIdx.x;
    int row  = gid >> 6;
    int lane = gid & 63;
    if (row >= nrows) return;
    int b = bin_base + row;
    int s = off[b];
    int e = off[b + 1];
    float acc = accumulate ? out[(size_t)row * DIM + lane] : 0.f;
    int k = s;
    for (; k + 4 <= e; k += 4) {
        uint r0 = rec[k], r1 = rec[k+1], r2 = rec[k+2], r3 = rec[k+3];
        ushort b0 = emb16[(size_t)(r0 >> 15) * DIM + lane];
        ushort b1 = emb16[(size_t)(r1 >> 15) * DIM + lane];
        ushort b2 = emb16[(size_t)(r2 >> 15) * DIM + lane];
        ushort b3 = emb16[(size_t)(r3 >> 15) * DIM + lane];
        acc += (float)(r0 & 0x7FFFu) * W_INV * __uint_as_float((uint)b0 << 16);
        acc += (float)(r1 & 0x7FFFu) * W_INV * __uint_as_float((uint)b1 << 16);
        acc += (float)(r2 & 0x7FFFu) * W_INV * __uint_as_float((uint)b2 << 16);
        acc += (float)(r3 & 0x7FFFu) * W_INV * __uint_as_float((uint)b3 << 16);
    }
    for (; k < e; ++k) {
        uint r0 = rec[k];
        ushort b0 = emb16[(size_t)(r0 >> 15) * DIM + lane];
        acc += (float)(r0 & 0x7FFFu) * W_INV * __uint_as_float((uint)b0 << 16);
    }
    out[(size_t)row * DIM + lane] = acc;
}

extern "C" void kernel_launch(void* const* d_in, const int* in_sizes, int n_in,
                              void* d_out, int out_size, void* d_ws, size_t ws_size,
                              hipStream_t stream) {
    const float* user_emb  = (const float*)d_in[0];
    const float* item_emb  = (const float*)d_in[1];
    const float* edge_norm = (const float*)d_in[2];
    const int*   u_idx     = (const int*)d_in[3];
    const int*   i_idx     = (const int*)d_in[4];

    float* agg_users = (float*)d_out;                        // 100000*64
    float* agg_items = agg_users + (size_t)NUM_USERS * DIM;  // 50000*64

    const int un4 = NUM_USERS * DIM / 4;
    const int in4 = NUM_ITEMS * DIM / 4;
    const int eb4 = (NUM_EDGES / 4 + 255) / 256;
    const int cb  = (un4 + in4 + 255) / 256;
    const size_t bf16_bytes = ((size_t)NUM_USERS + NUM_ITEMS) * DIM * sizeof(ushort);

    // ---------- tier 1: deterministic bucket partition -> local-scan CSR ----
    {
        const size_t off_bytes  = (size_t)(N_TOTAL + 1) * sizeof(int);
        const size_t buk_bytes  = (size_t)(2 * NBUK + 2) * sizeof(int);
        const size_t wgh_bytes  = (size_t)PWG * NBUK * sizeof(ushort);     // 1.4 MB
        const size_t wgp_bytes  = (size_t)NBUK * PWG * sizeof(uint);       // 2.9 MB
        const size_t prec_bytes = (size_t)2 * NUM_EDGES * sizeof(uint);    // 32 MB
        const size_t pbin_bytes = (size_t)2 * NUM_EDGES * sizeof(ushort);  // 16 MB
        const size_t rec_bytes  = (size_t)2 * NUM_EDGES * sizeof(uint);    // 32 MB
        const size_t need = off_bytes + buk_bytes + 64 + wgh_bytes + 64
                          + wgp_bytes + 64 + prec_bytes + 64 + pbin_bytes + 64
                          + rec_bytes + 64 + bf16_bytes + 256;
        if (ws_size >= need) {
            char* p = (char*)d_ws;
            int*    off     = (int*)p;    p += off_bytes;
            int*    bukTot  = (int*)p;    p += (size_t)NBUK * sizeof(int);
            int*    bukOff  = (int*)p;    p += (size_t)(NBUK + 1) * sizeof(int);
            p = (char*)(((uintptr_t)p + 63) & ~(uintptr_t)63);
            ushort* wgHist  = (ushort*)p; p += wgh_bytes;
            p = (char*)(((uintptr_t)p + 63) & ~(uintptr_t)63);
            uint*   wgPrefixT = (uint*)p; p += wgp_bytes;
            p = (char*)(((uintptr_t)p + 63) & ~(uintptr_t)63);
            uint*   pairRec = (uint*)p;   p += prec_bytes;
            p = (char*)(((uintptr_t)p + 63) & ~(uintptr_t)63);
            ushort* pairBin = (ushort*)p; p += pbin_bytes;
            p = (char*)(((uintptr_t)p + 63) & ~(uintptr_t)63);
            uint*   rec     = (uint*)p;   p += rec_bytes;
            p = (char*)(((uintptr_t)p + 63) & ~(uintptr_t)63);
            ushort* ue16    = (ushort*)p; p += (size_t)NUM_USERS * DIM * sizeof(ushort);
            ushort* ie16    = (ushort*)p;

            bucket_hist_conv<<<PWG + cb, 256, 0, stream>>>(
                u_idx, i_idx, wgHist,
                (const float4*)user_emb, (const float4*)item_emb,
                (ushort4*)ue16, (ushort4*)ie16, un4, in4, PWG);
            mscan<<<NBUK, 256, 0, stream>>>(wgHist, wgPrefixT, bukTot);
            bucket_scan<<<1, 256, 0, stream>>>(bukTot, bukOff, off + N_TOTAL);
            partition_pairs<<<PWG, 256, 0, stream>>>(
                u_idx, i_idx, edge_norm, wgHist, wgPrefixT, bukOff,
                pairRec, pairBin);
            bucket_fill<<<NBUK, BF_THREADS, 0, stream>>>(
                bukOff, pairRec, pairBin, off, rec);
            // merged phase-major gather, both directions, one launch
            const int gwaves = NUM_ITEMS / GW_ROWS + NUM_USERS / GW_ROWS; // 18750
            const int gblocks = (gwaves * 64 + 255) / 256;
            gather_pm<<<gblocks, 256, 0, stream>>>(
                off, rec, (const uint*)ue16, (const uint*)ie16,
                agg_users, agg_items);
            return;
        }
    }

    // ---------- tier 2/3: exact CSR via global atomics, sliced or not -------
    {
        const size_t rec_bytes  = (size_t)2 * NUM_EDGES * sizeof(uint);
        const size_t rank_bytes = (size_t)2 * NUM_EDGES * sizeof(int);
        auto need_for = [&](int SU, int SI) -> size_t {
            size_t n_total = (size_t)SU * NUM_ITEMS + (size_t)SI * NUM_USERS;
            size_t off_bytes = (n_total + 1 + 2 * SCAN_NB) * sizeof(int);
            return off_bytes + 64 + rec_bytes + 64 + rank_bytes + 64 + bf16_bytes
                 + 256;
        };
        int SU = 0, SI = 0, su_shift = 17, si_shift = 17;
        if (ws_size >= need_for(SLICES_U, SLICES_I)) {
            SU = SLICES_U; SI = SLICES_I;
            su_shift = SLICE_SHIFT; si_shift = SLICE_SHIFT;
        } else if (ws_size >= need_for(1, 1)) {
            SU = 1; SI = 1;
        }
        if (SU > 0) {
            const int n_i = SU * NUM_ITEMS;
            const int n_u = SI * NUM_USERS;
            const int n_total = n_i + n_u;

            char* p = (char*)d_ws;
            int*   cnt  = (int*)p;   p += (size_t)(n_total + 1) * sizeof(int);
            int*   bsum = (int*)p;   p += (size_t)SCAN_NB * sizeof(int);
            int*   boff = (int*)p;   p += (size_t)SCAN_NB * sizeof(int);
            p = (char*)(((uintptr_t)p + 63) & ~(uintptr_t)63);
            uint*  rec  = (uint*)p;  p += rec_bytes;
            p = (char*)(((uintptr_t)p + 63) & ~(uintptr_t)63);
            int*   rank_i = (int*)p; p += (size_t)NUM_EDGES * sizeof(int);
            int*   rank_u = (int*)p; p += (size_t)NUM_EDGES * sizeof(int);
            p = (char*)(((uintptr_t)p + 63) & ~(uintptr_t)63);
            ushort* ue16 = (ushort*)p; p += (size_t)NUM_USERS * DIM * sizeof(ushort);
            ushort* ie16 = (ushort*)p;

            hipMemsetAsync(cnt, 0, (size_t)(n_total + 1) * sizeof(int), stream);
            convert_both<<<cb, 256, 0, stream>>>(
                (const float4*)user_emb, (const float4*)item_emb,
                (ushort4*)ue16, (ushort4*)ie16, un4, in4);
            rank_both_exact<<<eb4, 256, 0, stream>>>(
                (const int4*)u_idx, (const int4*)i_idx, cnt, n_i,
                su_shift, si_shift, (int4*)rank_i, (int4*)rank_u);
            const int chunk = (n_total + SCAN_NB - 1) / SCAN_NB;
            scan_block_sums<<<SCAN_NB, SCAN_THREADS, 0, stream>>>(
                cnt, bsum, n_total, chunk);
            scan_block_offsets<<<1, SCAN_NB, 0, stream>>>(bsum, boff, cnt + n_total);
            scan_local<<<SCAN_NB, SCAN_THREADS, 0, stream>>>(
                cnt, boff, n_total, chunk);
            scatter_all<<<eb4, 256, 0, stream>>>(
                (const int4*)u_idx, (const int4*)i_idx, (const float4*)edge_norm,
                (const int4*)rank_i, (const int4*)rank_u,
                cnt, n_i, su_shift, si_shift, rec);
            for (int s = 0; s < SU; ++s) {
                gather_pass<<<((NUM_ITEMS * 64) + 255) / 256, 256, 0, stream>>>(
                    cnt, s * NUM_ITEMS, rec, ue16, agg_items, NUM_ITEMS,
                    s > 0 ? 1 : 0);
            }
            for (int s = 0; s < SI; ++s) {
                gather_pass<<<((NUM_USERS * 64) + 255) / 256, 256, 0, stream>>>(
                    cnt, n_i + s * NUM_USERS, rec, ie16, agg_users, NUM_USERS,
                    s > 0 ? 1 : 0);
            }
            return;
        }
    }

    // ---------- tier 4: scatter-atomic ----------
    hipMemsetAsync(d_out, 0, (size_t)out_size * sizeof(float), stream);
    const long long total_threads = (long long)NUM_EDGES * 64;
    const int blocks = (int)((total_threads + 255) / 256);
    lightgcn_scatter<<<blocks, 256, 0, stream>>>(
        user_emb, item_emb, edge_norm, u_idx, i_idx, agg_users, agg_items);
}